// Round 18
// baseline (278.415 us; speedup 1.0000x reference)
//
#include <hip/hip_runtime.h>
#include <stdint.h>

#define TDIM 2048
#define DMODEL 2048
#define NHEADS 16
#define DHEAD 128
#define NBATCH 2
#define NTOK (NBATCH * TDIM)   // 4096
#define NQKV (3 * DMODEL)      // 6144
#define BHTOT (NBATCH * NHEADS) // 32

typedef unsigned short u16;
typedef __attribute__((ext_vector_type(8))) short bf16x8;
typedef __attribute__((ext_vector_type(4))) float f32x4;
typedef __attribute__((ext_vector_type(4))) int i32x4;

__device__ __forceinline__ u16 f2bf(float f) {
  union { float f; uint32_t u; } v; v.f = f;
  uint32_t u = v.u + 0x7fffu + ((v.u >> 16) & 1u);
  return (u16)(u >> 16);
}
__device__ __forceinline__ float bf2f(u16 h) {
  union { uint32_t u; float f; } v; v.u = ((uint32_t)h) << 16;
  return v.f;
}

#define GLOAD16(g, l)                                                        \
  __builtin_amdgcn_global_load_lds(                                          \
      (const __attribute__((address_space(1))) void*)(g),                    \
      (__attribute__((address_space(3))) void*)(l), 16, 0, 0)

// ---------------- merged prep: rope table + convert + 2 transposes --------
__device__ __forceinline__ void tc_tile(const float* __restrict__ in,
                                        u16* __restrict__ out, int K, int N,
                                        int n0, int k0, int t) {
  __shared__ u16 tile[64][65];
  #pragma unroll
  for (int q = 0; q < 4; q++) {
    int idx = q * 1024 + t * 4;        // 0..4095 over the 64x64 tile
    int k = idx >> 6, n = idx & 63;
    float4 v = *(const float4*)&in[(size_t)(k0 + k) * N + n0 + n];
    tile[k][n]     = f2bf(v.x);
    tile[k][n + 1] = f2bf(v.y);
    tile[k][n + 2] = f2bf(v.z);
    tile[k][n + 3] = f2bf(v.w);
  }
  __syncthreads();
  #pragma unroll
  for (int q = 0; q < 4; q++) {
    int n = (t >> 4) + q * 16;         // 0..63
    int k4 = (t & 15) * 4;             // 0,4,...,60
    ushort4 o;
    o.x = tile[k4][n];     o.y = tile[k4 + 1][n];
    o.z = tile[k4 + 2][n]; o.w = tile[k4 + 3][n];
    *(ushort4*)&out[(size_t)(n0 + n) * K + k0 + k4] = o;
  }
}

__global__ __launch_bounds__(256) void prep_kernel(
    const float* __restrict__ x, u16* __restrict__ xb,
    const float* __restrict__ Wqkv, u16* __restrict__ Wqkvt,
    const float* __restrict__ Wo, u16* __restrict__ Wot,
    float* __restrict__ ct, float* __restrict__ st) {
  const int bid = blockIdx.x;
  const int t = threadIdx.x;
  if (bid < 512) {
    int idx = bid * 256 + t;           // TDIM*64 total
    int tt = idx >> 6, m = idx & 63;
    float inv = expf(-(float)m * (9.210340371976184f / 64.0f));
    float ang = (float)tt * inv;
    ct[idx] = cosf(ang);
    st[idx] = sinf(ang);
  } else if (bid < 8704) {
    int i = (bid - 512) * 256 + t;     // NTOK*DMODEL/4 elements
    float4 v = ((const float4*)x)[i];
    ushort4 o;
    o.x = f2bf(v.x); o.y = f2bf(v.y); o.z = f2bf(v.z); o.w = f2bf(v.w);
    ((ushort4*)xb)[i] = o;
  } else if (bid < 11776) {
    int tb = bid - 8704;               // Wqkv: 96 x-tiles, 32 y-tiles
    int bx = tb % 96, by = tb / 96;
    tc_tile(Wqkv, Wqkvt, DMODEL, NQKV, bx * 64, by * 64, t);
  } else {
    int tb = bid - 11776;              // Wo: 32 x 32 tiles
    int bx = tb & 31, by = tb >> 5;
    tc_tile(Wo, Wot, DMODEL, DMODEL, bx * 64, by * 64, t);
  }
}

// ---------------- deep-pipelined GEMM: A (M,K) @ Bt (N,K), bf16 -----------
// R3-proven SCHEDULE at BM=BN=128 BK=64, 256 threads (4 waves 2x2), dbuf
// 64KB LDS -> 2 blocks/CU (cross-block TLP covers barrier drains, m114).
// Counted-vmcnt prefetch (8 loads/stage), T2 XOR chunk-swizzle, SUB1/SUB2
// split, setprio (T5). NO XCD swizzle (R7).
// MODE 0: + bias, fused RoPE on Q/K; V direct-transposed to Vt[b][h][d][t].
// MODE 1: + bias -> fp32 row-major out (N=DMODEL)
template <int MODE>
__global__ __launch_bounds__(256, 2) void gemm_bt_kernel(
    const u16* __restrict__ A, const u16* __restrict__ Bt,
    const float* __restrict__ bias,
    u16* __restrict__ q_out, u16* __restrict__ k_out, u16* __restrict__ v_out,
    float* __restrict__ f_out,
    const float* __restrict__ ct, const float* __restrict__ st, int K) {
  // per buffer: A 128x64 bf16 = 16384 B, B 128x64 bf16 = 16384 B
  __shared__ __attribute__((aligned(128))) char lds[2][32768];
  const int tid = threadIdx.x;
  const int lane = tid & 63, w = tid >> 6;
  const int wr = w >> 1, wc = w & 1;          // wave grid 2 x 2
  const int g = lane >> 4, c = lane & 15;
  const int m0 = blockIdx.x * 128, n0 = blockIdx.y * 128;
  const size_t rowb = (size_t)K * 2;
  const int NKT = K >> 6;

  // ---- per-thread staging sources (pre-swizzled global chunks, rule 21) ----
  // 8 load-instrs/thread/tile: idx 0-3 = A (16KB), 4-7 = B (16KB).
  const char* sSrc[8]; int sDst[8];
  #pragma unroll
  for (int p = 0; p < 4; p++) {
    int o = p * 4096 + tid * 16;
    int row = o >> 7, j = (o >> 4) & 7;
    sSrc[p] = (const char*)A + (size_t)(m0 + row) * rowb + ((j ^ (row & 7)) << 4);
    sDst[p] = o;
    sSrc[4 + p] = (const char*)Bt + (size_t)(n0 + row) * rowb +
                  ((j ^ (row & 7)) << 4);
    sDst[4 + p] = 16384 + o;
  }

#define STAGE(bufp, kt)                                                      \
  {                                                                          \
    const size_t kb_ = (size_t)(kt) * 128;                                   \
    _Pragma("unroll") for (int p_ = 0; p_ < 8; p_++)                         \
        GLOAD16(sSrc[p_] + kb_, (bufp) + sDst[p_]);                          \
  }

  // ---- per-wave LDS fragment read offsets (swizzled) ----
  int aRd[4][2], bRd[4][2];
  #pragma unroll
  for (int m = 0; m < 4; m++) {
    #pragma unroll
    for (int ks = 0; ks < 2; ks++) {
      int arow = wr * 64 + m * 16 + c;
      aRd[m][ks] = arow * 128 + (((ks * 4 + g) ^ (c & 7)) << 4);
      int brow = wc * 64 + m * 16 + c;
      bRd[m][ks] = 16384 + brow * 128 + (((ks * 4 + g) ^ (c & 7)) << 4);
    }
  }

  const f32x4 zero = {0.f, 0.f, 0.f, 0.f};
  f32x4 acc[4][4];
  #pragma unroll
  for (int m = 0; m < 4; m++)
    #pragma unroll
    for (int n = 0; n < 4; n++) acc[m][n] = zero;

  // ---- prologue: 2 tiles in flight, wait the first (8 newest in flight) ----
  STAGE(lds[0], 0);
  STAGE(lds[1], 1);
  asm volatile("s_waitcnt vmcnt(8)" ::: "memory");
  __builtin_amdgcn_s_barrier();
  __builtin_amdgcn_sched_barrier(0);

  for (int kt = 0; kt < NKT; kt++) {
    char* bp = lds[kt & 1];
    bf16x8 bfr[4][2], afr[2][2], af2[2][2];
    // SUB1: B frags (all) + A frags m=0..1, then 16 MFMA
    #pragma unroll
    for (int n = 0; n < 4; n++)
      #pragma unroll
      for (int ks = 0; ks < 2; ks++)
        bfr[n][ks] = *(const bf16x8*)(bp + bRd[n][ks]);
    #pragma unroll
    for (int m = 0; m < 2; m++)
      #pragma unroll
      for (int ks = 0; ks < 2; ks++)
        afr[m][ks] = *(const bf16x8*)(bp + aRd[m][ks]);
    __builtin_amdgcn_s_setprio(1);
    #pragma unroll
    for (int ks = 0; ks < 2; ks++)
      #pragma unroll
      for (int m = 0; m < 2; m++)
        #pragma unroll
        for (int n = 0; n < 4; n++)
          acc[m][n] = __builtin_amdgcn_mfma_f32_16x16x32_bf16(
              afr[m][ks], bfr[n][ks], acc[m][n], 0, 0, 0);
    __builtin_amdgcn_s_setprio(0);

    // SUB2: A frags m=2..3, retire all reads, barrier, re-stage, 16 MFMA
    #pragma unroll
    for (int m = 0; m < 2; m++)
      #pragma unroll
      for (int ks = 0; ks < 2; ks++)
        af2[m][ks] = *(const bf16x8*)(bp + aRd[m + 2][ks]);
    asm volatile("s_waitcnt lgkmcnt(0)" ::: "memory");
    __builtin_amdgcn_s_barrier();           // all waves done READING bp
    __builtin_amdgcn_sched_barrier(0);
    if (kt + 2 < NKT) STAGE(bp, kt + 2);    // overwrite freed buffer
    __builtin_amdgcn_s_setprio(1);
    #pragma unroll
    for (int ks = 0; ks < 2; ks++)
      #pragma unroll
      for (int m = 0; m < 2; m++)
        #pragma unroll
        for (int n = 0; n < 4; n++)
          acc[m + 2][n] = __builtin_amdgcn_mfma_f32_16x16x32_bf16(
              af2[m][ks], bfr[n][ks], acc[m + 2][n], 0, 0, 0);
    __builtin_amdgcn_s_setprio(0);

    if (kt < NKT - 1) {
      // tile kt+1's 8 loads must land; keep kt+2's 8 in flight (T4).
      if (kt + 2 < NKT) {
        asm volatile("s_waitcnt vmcnt(8)" ::: "memory");
      } else {
        asm volatile("s_waitcnt vmcnt(0)" ::: "memory");
      }
      __builtin_amdgcn_s_barrier();
      __builtin_amdgcn_sched_barrier(0);
    }
  }
#undef STAGE

  // ---- epilogue: D row=(lane>>4)*4+r (A rows), col=lane&15 (B rows) ----
  #pragma unroll
  for (int m = 0; m < 4; m++) {
    #pragma unroll
    for (int n = 0; n < 4; n++) {
      int gcol = n0 + wc * 64 + n * 16 + c;
      float bv = bias[gcol];
      float val[4];
      #pragma unroll
      for (int r = 0; r < 4; r++) val[r] = acc[m][n][r] + bv;
      if (MODE == 0) {
        int s = n0 >> 11;                // 0:q 1:k 2:v (uniform per block)
        int rem = gcol & 2047;
        int h = rem >> 7, d = rem & 127;
        int growb = m0 + wr * 64 + m * 16;
        int b0 = growb >> 11;            // uniform within the 16-row frag
        if (s == 2) {
          // V direct-transposed: Vt[(b*16+h)*128 + d][t], 4 consecutive t
          size_t vb = (((size_t)(b0 * NHEADS + h)) * DHEAD + d) * TDIM;
          int t0 = (growb & (TDIM - 1)) + g * 4;
          ushort4 pk;
          pk.x = f2bf(val[0]); pk.y = f2bf(val[1]);
          pk.z = f2bf(val[2]); pk.w = f2bf(val[3]);
          *(ushort4*)(v_out + vb + t0) = pk;
        } else {
          // fused RoPE: pairs (d, d^1) live in lanes (c, c^1)
          size_t hb = (((size_t)(b0 * NHEADS + h)) * TDIM) * DHEAD + d;
          int mf = gcol & 63;            // freq index = d & 63
          float sgn = (c & 1) ? 1.0f : -1.0f;
          u16* dst = (s == 0) ? q_out : k_out;
          float qs = (s == 0) ? 0.08838834764831845f : 1.0f;
          #pragma unroll
          for (int r = 0; r < 4; r++) {
            float part = __shfl_xor(val[r], 1, 64);
            int t = (growb + g * 4 + r) & (TDIM - 1);
            float cs = ct[t * 64 + mf], sn = st[t * 64 + mf];
            float rot = (val[r] * cs + sgn * part * sn) * qs;
            dst[hb + (size_t)t * DHEAD] = f2bf(rot);
          }
        }
      } else {
        #pragma unroll
        for (int r = 0; r < 4; r++) {
          int grow = m0 + wr * 64 + m * 16 + g * 4 + r;
          f_out[(size_t)grow * DMODEL + gcol] = val[r];
        }
      }
    }
  }
}

// ---------------- Flash attention (causal), 4 waves x 16 q-rows -----------
// R16-proven: K and V both double-buffered; tile t+1 (K+V) staged at
// iteration TOP into buffers [cur^1]; per-iter sync = 1 lgkmcnt + 1 vmcnt +
// 1 barrier. Causal-paired q-tiles {i, 31-i}. LDS 72KB -> 2 blocks/CU.
// Q,K: [BH][T][128] bf16 (Q pre-scaled); Vt: [BH][128][T]; Yattn: [B][T][HD]
__global__ __launch_bounds__(256) void attn_kernel(
    const u16* __restrict__ Q, const u16* __restrict__ K,
    const u16* __restrict__ Vt, u16* __restrict__ Yattn) {
  __shared__ u16 Ks[2][64 * 128]; // [kv][d], swizzle chunk^=(row&7) (2x16KB)
  __shared__ u16 Vs[2][128 * 64]; // [d][kv], swizzle chunk^=(row&7) (2x16KB)
  __shared__ u16 Ps[4][16 * 64];  // per-wave P tile, swizzled (8 KB)
  const int tid = threadIdx.x, lane = tid & 63, w = tid >> 6;
  const int g = lane >> 4, c = lane & 15;
  const int bh = blockIdx.y, b = bh >> 4, h = bh & 15;
  const u16* Qp = Q + (size_t)bh * TDIM * DHEAD;
  const u16* Kp = K + (size_t)bh * TDIM * DHEAD;
  const u16* Vp = Vt + (size_t)bh * DHEAD * TDIM;
  const f32x4 zero = {0.f, 0.f, 0.f, 0.f};

#define STAGE_K(kv0, buf)                                                    \
  {                                                                          \
    _Pragma("unroll") for (int p_ = 0; p_ < 4; p_++) {                       \
      int off = p_ * 4096 + tid * 16;                                        \
      int kr = off >> 8, kc4 = (off & 255) >> 4;                             \
      GLOAD16((const char*)Kp + (size_t)((kv0) + kr) * 256 +                 \
                  ((kc4 ^ (kr & 7)) << 4),                                   \
              (char*)Ks[buf] + off);                                         \
    }                                                                        \
  }
#define STAGE_V(kv0, buf)                                                    \
  {                                                                          \
    _Pragma("unroll") for (int p_ = 0; p_ < 4; p_++) {                       \
      int off = p_ * 4096 + tid * 16;                                        \
      int vr = off >> 7, vc4 = (off & 127) >> 4;                             \
      GLOAD16((const char*)Vp + (size_t)vr * (TDIM * 2) + (size_t)(kv0) * 2 +\
                  ((vc4 ^ (vr & 7)) << 4),                                   \
              (char*)Vs[buf] + off);                                         \
    }                                                                        \
  }

  for (int half = 0; half < 2; half++) {
    const int qt = half ? (31 - (int)blockIdx.x) : (int)blockIdx.x;
    const int qb = qt * 64 + w * 16;

    bf16x8 qf[4];
    #pragma unroll
    for (int kc = 0; kc < 4; kc++)
      qf[kc] = *(const bf16x8*)(Qp + (size_t)(qb + c) * DHEAD + kc * 32 + g * 8);

    f32x4 po[8];
    #pragma unroll
    for (int df = 0; df < 8; df++) po[df] = zero;
    float mrun[4], lrun[4];
    #pragma unroll
    for (int r = 0; r < 4; r++) { mrun[r] = -1e30f; lrun[r] = 0.f; }

    const int nt = qt + 1;

    // ---- prologue: stage tile 0 (K+V) into buf 0; wait landed ----
    STAGE_K(0, 0);
    STAGE_V(0, 0);
    asm volatile("s_waitcnt vmcnt(0)" ::: "memory");
    __builtin_amdgcn_s_barrier();
    __builtin_amdgcn_sched_barrier(0);

    int cur = 0;
    for (int t = 0; t < nt; t++) {
      const int kv0 = t * 64;
      const bool more = (t + 1 < nt);

      // ---- issue full tile t+1 prefetch (K then V) into other buffers ----
      if (more) {
        STAGE_K(kv0 + 64, cur ^ 1);
        STAGE_V(kv0 + 64, cur ^ 1);
      }

      // ---- S = Q @ K^T (16 x 64 per wave) reads Ks[cur] ----
      const u16* KsC = Ks[cur];
      const u16* VsC = Vs[cur];
      f32x4 sa[4];
      #pragma unroll
      for (int n = 0; n < 4; n++) sa[n] = zero;
      __builtin_amdgcn_s_setprio(1);
      #pragma unroll
      for (int n = 0; n < 4; n++) {
        int krow = n * 16 + c;
        #pragma unroll
        for (int kc = 0; kc < 4; kc++) {
          int kb = (kc * 32 + g * 8) * 2;
          bf16x8 kf = *(const bf16x8*)((const char*)KsC + krow * 256 +
                                       (kb ^ ((krow & 7) << 4)));
          sa[n] = __builtin_amdgcn_mfma_f32_16x16x32_bf16(qf[kc], kf, sa[n], 0, 0, 0);
        }
      }
      __builtin_amdgcn_s_setprio(0);

      // ---- causal mask (only tiles straddling the diagonal) ----
      if (kv0 + 63 > qb) {
        #pragma unroll
        for (int n = 0; n < 4; n++) {
          int col = kv0 + n * 16 + c;
          #pragma unroll
          for (int r = 0; r < 4; r++) {
            int qrow = qb + g * 4 + r;
            if (col > qrow) sa[n][r] = -1e30f;
          }
        }
      }

      // ---- online softmax (rows g*4+r, cols n*16+c) ----
      float pvals[4][4];
      #pragma unroll
      for (int r = 0; r < 4; r++) {
        float vmax = fmaxf(fmaxf(sa[0][r], sa[1][r]), fmaxf(sa[2][r], sa[3][r]));
        #pragma unroll
        for (int d = 1; d < 16; d <<= 1) vmax = fmaxf(vmax, __shfl_xor(vmax, d, 64));
        float mnew = fmaxf(mrun[r], vmax);
        float scale = __expf(mrun[r] - mnew);
        float rs = 0.f;
        #pragma unroll
        for (int n = 0; n < 4; n++) {
          float p = __expf(sa[n][r] - mnew);
          pvals[r][n] = p;
          rs += p;
        }
        #pragma unroll
        for (int d = 1; d < 16; d <<= 1) rs += __shfl_xor(rs, d, 64);
        lrun[r] = lrun[r] * scale + rs;
        mrun[r] = mnew;
        #pragma unroll
        for (int df = 0; df < 8; df++) po[df][r] *= scale;
      }

      // ---- P -> LDS (per-wave, swizzled), then PV reads Vs[cur] ----
      char* Pw = (char*)&Ps[w][0];
      #pragma unroll
      for (int r = 0; r < 4; r++) {
        int ri = g * 4 + r;
        #pragma unroll
        for (int n = 0; n < 4; n++) {
          int colb = (n * 16 + c) * 2;
          *(u16*)(Pw + ri * 128 + (colb ^ ((ri & 7) << 4))) = f2bf(pvals[r][n]);
        }
      }
      bf16x8 pa[2];
      #pragma unroll
      for (int kc2 = 0; kc2 < 2; kc2++) {
        int pb = (kc2 * 32 + g * 8) * 2;
        pa[kc2] = *(const bf16x8*)(Pw + c * 128 + (pb ^ ((c & 7) << 4)));
      }
      __builtin_amdgcn_s_setprio(1);
      #pragma unroll
      for (int df = 0; df < 8; df++) {
        #pragma unroll
        for (int kc2 = 0; kc2 < 2; kc2++) {
          int vrow = df * 16 + c;
          int vb = (kc2 * 32 + g * 8) * 2;
          bf16x8 vf = *(const bf16x8*)((const char*)VsC + vrow * 128 +
                                       (vb ^ ((vrow & 7) << 4)));
          po[df] = __builtin_amdgcn_mfma_f32_16x16x32_bf16(pa[kc2], vf, po[df], 0, 0, 0);
        }
      }
      __builtin_amdgcn_s_setprio(0);

      // ---- single sync point per iteration ----
      asm volatile("s_waitcnt lgkmcnt(0)" ::: "memory"); // own LDS reads done
      if (more) {
        asm volatile("s_waitcnt vmcnt(0)" ::: "memory"); // own t+1 loads landed
      }
      __builtin_amdgcn_s_barrier();  // all waves: reads retired, writes visible
      __builtin_amdgcn_sched_barrier(0);
      cur ^= 1;
    }

    float inv[4];
    #pragma unroll
    for (int r = 0; r < 4; r++) inv[r] = 1.0f / lrun[r];
    #pragma unroll
    for (int df = 0; df < 8; df++) {
      #pragma unroll
      for (int r = 0; r < 4; r++) {
        int trow = qb + g * 4 + r;
        int col = h * DHEAD + df * 16 + c;
        Yattn[((size_t)b * TDIM + trow) * DMODEL + col] = f2bf(po[df][r] * inv[r]);
      }
    }
    // half-boundary: last iter ended with lgkmcnt(0)+barrier and no loads
    // outstanding -> next half's prologue staging (into buf0) is safe.
  }
#undef STAGE_K
#undef STAGE_V
}

extern "C" void kernel_launch(void* const* d_in, const int* in_sizes, int n_in,
                              void* d_out, int out_size, void* d_ws, size_t ws_size,
                              hipStream_t stream) {
  const float* x    = (const float*)d_in[0];
  // d_in[1] = mask (exact causal triu; implemented analytically)
  const float* Wqkv = (const float*)d_in[2];
  const float* bqkv = (const float*)d_in[3];
  const float* Wo   = (const float*)d_in[4];
  const float* bo   = (const float*)d_in[5];
  float* out = (float*)d_out;

  char* ws = (char*)d_ws;
  size_t o = 0;
  u16* xb    = (u16*)(ws + o); o += (size_t)NTOK * DMODEL * 2;     // 16.8 MB
  u16* Wqkvt = (u16*)(ws + o); o += (size_t)NQKV * DMODEL * 2;     // 25.2 MB
  u16* Wot   = (u16*)(ws + o); o += (size_t)DMODEL * DMODEL * 2;   // 8.4 MB
  u16* Qb    = (u16*)(ws + o); o += (size_t)BHTOT * TDIM * DHEAD * 2;
  u16* Kb    = (u16*)(ws + o); o += (size_t)BHTOT * TDIM * DHEAD * 2;
  u16* Vt    = (u16*)(ws + o); o += (size_t)BHTOT * TDIM * DHEAD * 2;
  float* ct  = (float*)(ws + o); o += (size_t)TDIM * 64 * 4;
  float* st  = (float*)(ws + o); o += (size_t)TDIM * 64 * 4;
  u16* Yattn = xb;    // alias: xb dead after GEMM1

  // one fused prep dispatch: rope table + x convert + both W transposes
  prep_kernel<<<12800, 256, 0, stream>>>(x, xb, Wqkv, Wqkvt, Wo, Wot, ct, st);

  // BM=BN=128: grid1 = 32x48 = 1536 blocks (3 rounds at 2 blocks/CU);
  // RoPE fused on Q/K, V written direct-transposed (no vtrans kernel).
  gemm_bt_kernel<0><<<dim3(NTOK / 128, NQKV / 128), 256, 0, stream>>>(
      xb, Wqkvt, bqkv, Qb, Kb, Vt, nullptr, ct, st, DMODEL);

  // causal-paired q-tiles: grid.x = 16 pairs, each block does {i, 31-i}
  attn_kernel<<<dim3(16, BHTOT), 256, 0, stream>>>(Qb, Kb, Vt, Yattn);

  // grid2 = 32x16 = 512 blocks (1 round at 2 blocks/CU)
  gemm_bt_kernel<1><<<dim3(NTOK / 128, DMODEL / 128), 256, 0, stream>>>(
      Yattn, Wot, bo, nullptr, nullptr, nullptr, out, nullptr, nullptr, DMODEL);
}

// Round 19
// 272.333 us; speedup vs baseline: 1.0223x; 1.0223x over previous
//
#include <hip/hip_runtime.h>
#include <stdint.h>

#define TDIM 2048
#define DMODEL 2048
#define NHEADS 16
#define DHEAD 128
#define NBATCH 2
#define NTOK (NBATCH * TDIM)   // 4096
#define NQKV (3 * DMODEL)      // 6144
#define BHTOT (NBATCH * NHEADS) // 32

typedef unsigned short u16;
typedef __attribute__((ext_vector_type(8))) short bf16x8;
typedef __attribute__((ext_vector_type(4))) float f32x4;
typedef __attribute__((ext_vector_type(4))) int i32x4;

__device__ __forceinline__ u16 f2bf(float f) {
  union { float f; uint32_t u; } v; v.f = f;
  uint32_t u = v.u + 0x7fffu + ((v.u >> 16) & 1u);
  return (u16)(u >> 16);
}
__device__ __forceinline__ float bf2f(u16 h) {
  union { uint32_t u; float f; } v; v.u = ((uint32_t)h) << 16;
  return v.f;
}

#define GLOAD16(g, l)                                                        \
  __builtin_amdgcn_global_load_lds(                                          \
      (const __attribute__((address_space(1))) void*)(g),                    \
      (__attribute__((address_space(3))) void*)(l), 16, 0, 0)

// ---------------- merged prep: rope table + convert + 2 transposes --------
__device__ __forceinline__ void tc_tile(const float* __restrict__ in,
                                        u16* __restrict__ out, int K, int N,
                                        int n0, int k0, int t) {
  __shared__ u16 tile[64][65];
  #pragma unroll
  for (int q = 0; q < 4; q++) {
    int idx = q * 1024 + t * 4;        // 0..4095 over the 64x64 tile
    int k = idx >> 6, n = idx & 63;
    float4 v = *(const float4*)&in[(size_t)(k0 + k) * N + n0 + n];
    tile[k][n]     = f2bf(v.x);
    tile[k][n + 1] = f2bf(v.y);
    tile[k][n + 2] = f2bf(v.z);
    tile[k][n + 3] = f2bf(v.w);
  }
  __syncthreads();
  #pragma unroll
  for (int q = 0; q < 4; q++) {
    int n = (t >> 4) + q * 16;         // 0..63
    int k4 = (t & 15) * 4;             // 0,4,...,60
    ushort4 o;
    o.x = tile[k4][n];     o.y = tile[k4 + 1][n];
    o.z = tile[k4 + 2][n]; o.w = tile[k4 + 3][n];
    *(ushort4*)&out[(size_t)(n0 + n) * K + k0 + k4] = o;
  }
}

__global__ __launch_bounds__(256) void prep_kernel(
    const float* __restrict__ x, u16* __restrict__ xb,
    const float* __restrict__ Wqkv, u16* __restrict__ Wqkvt,
    const float* __restrict__ Wo, u16* __restrict__ Wot,
    float* __restrict__ ct, float* __restrict__ st) {
  const int bid = blockIdx.x;
  const int t = threadIdx.x;
  if (bid < 512) {
    int idx = bid * 256 + t;           // TDIM*64 total
    int tt = idx >> 6, m = idx & 63;
    float inv = expf(-(float)m * (9.210340371976184f / 64.0f));
    float ang = (float)tt * inv;
    ct[idx] = cosf(ang);
    st[idx] = sinf(ang);
  } else if (bid < 8704) {
    int i = (bid - 512) * 256 + t;     // NTOK*DMODEL/4 elements
    float4 v = ((const float4*)x)[i];
    ushort4 o;
    o.x = f2bf(v.x); o.y = f2bf(v.y); o.z = f2bf(v.z); o.w = f2bf(v.w);
    ((ushort4*)xb)[i] = o;
  } else if (bid < 11776) {
    int tb = bid - 8704;               // Wqkv: 96 x-tiles, 32 y-tiles
    int bx = tb % 96, by = tb / 96;
    tc_tile(Wqkv, Wqkvt, DMODEL, NQKV, bx * 64, by * 64, t);
  } else {
    int tb = bid - 11776;              // Wo: 32 x 32 tiles
    int bx = tb & 31, by = tb >> 5;
    tc_tile(Wo, Wot, DMODEL, DMODEL, bx * 64, by * 64, t);
  }
}

// ---------------- m97-style GEMM: A (M,K) @ Bt (N,K), bf16 ----------------
// 128x128 tile, BK=64, 256 threads (4 waves 2x2), SINGLE-buffered 32KB LDS
// -> 4 blocks/CU (16 waves/CU): cross-block TLP hides the per-tile vmcnt(0)
// drain (m114/m97: this config measured 912 TF ref-checked). Plain 2-barrier
// K-loop; T2 XOR chunk-swizzle both-sides; SUB1/SUB2 frag split keeps VGPR
// ~88; setprio around MFMA (T5). NO XCD swizzle (R7).
// MODE 0: + bias, fused RoPE on Q/K; V direct-transposed to Vt[b][h][d][t].
// MODE 1: + bias -> fp32 row-major out (N=DMODEL)
template <int MODE>
__global__ __launch_bounds__(256) void gemm_bt_kernel(
    const u16* __restrict__ A, const u16* __restrict__ Bt,
    const float* __restrict__ bias,
    u16* __restrict__ q_out, u16* __restrict__ k_out, u16* __restrict__ v_out,
    float* __restrict__ f_out,
    const float* __restrict__ ct, const float* __restrict__ st, int K) {
  // A 128x64 bf16 = 16384 B, B 128x64 bf16 = 16384 B -> 32 KB total
  __shared__ __attribute__((aligned(128))) char lds[32768];
  const int tid = threadIdx.x;
  const int lane = tid & 63, w = tid >> 6;
  const int wr = w >> 1, wc = w & 1;          // wave grid 2 x 2
  const int g = lane >> 4, c = lane & 15;
  const int m0 = blockIdx.x * 128, n0 = blockIdx.y * 128;
  const size_t rowb = (size_t)K * 2;
  const int NKT = K >> 6;

  // ---- per-thread staging sources (pre-swizzled global chunks, rule 21) ----
  // 8 load-instrs/thread/tile: idx 0-3 = A (16KB), 4-7 = B (16KB).
  const char* sSrc[8]; int sDst[8];
  #pragma unroll
  for (int p = 0; p < 4; p++) {
    int o = p * 4096 + tid * 16;
    int row = o >> 7, j = (o >> 4) & 7;
    sSrc[p] = (const char*)A + (size_t)(m0 + row) * rowb + ((j ^ (row & 7)) << 4);
    sDst[p] = o;
    sSrc[4 + p] = (const char*)Bt + (size_t)(n0 + row) * rowb +
                  ((j ^ (row & 7)) << 4);
    sDst[4 + p] = 16384 + o;
  }

#define STAGE(kt)                                                            \
  {                                                                          \
    const size_t kb_ = (size_t)(kt) * 128;                                   \
    _Pragma("unroll") for (int p_ = 0; p_ < 8; p_++)                         \
        GLOAD16(sSrc[p_] + kb_, lds + sDst[p_]);                             \
  }

  // ---- per-wave LDS fragment read offsets (swizzled) ----
  int aRd[4][2], bRd[4][2];
  #pragma unroll
  for (int m = 0; m < 4; m++) {
    #pragma unroll
    for (int ks = 0; ks < 2; ks++) {
      int arow = wr * 64 + m * 16 + c;
      aRd[m][ks] = arow * 128 + (((ks * 4 + g) ^ (c & 7)) << 4);
      int brow = wc * 64 + m * 16 + c;
      bRd[m][ks] = 16384 + brow * 128 + (((ks * 4 + g) ^ (c & 7)) << 4);
    }
  }

  const f32x4 zero = {0.f, 0.f, 0.f, 0.f};
  f32x4 acc[4][4];
  #pragma unroll
  for (int m = 0; m < 4; m++)
    #pragma unroll
    for (int n = 0; n < 4; n++) acc[m][n] = zero;

  for (int kt = 0; kt < NKT; kt++) {
    if (kt) {
      // all waves' reads of tile kt-1 retired (register deps guarantee the
      // ds_reads completed before their consuming MFMAs issued)
      asm volatile("s_waitcnt lgkmcnt(0)" ::: "memory");
      __builtin_amdgcn_s_barrier();
      __builtin_amdgcn_sched_barrier(0);
    }
    STAGE(kt);
    asm volatile("s_waitcnt vmcnt(0)" ::: "memory");
    __builtin_amdgcn_s_barrier();
    __builtin_amdgcn_sched_barrier(0);

    bf16x8 bfr[4][2], afr[2][2], af2[2][2];
    // SUB1: B frags (all) + A frags m=0..1, then 16 MFMA
    #pragma unroll
    for (int n = 0; n < 4; n++)
      #pragma unroll
      for (int ks = 0; ks < 2; ks++)
        bfr[n][ks] = *(const bf16x8*)(lds + bRd[n][ks]);
    #pragma unroll
    for (int m = 0; m < 2; m++)
      #pragma unroll
      for (int ks = 0; ks < 2; ks++)
        afr[m][ks] = *(const bf16x8*)(lds + aRd[m][ks]);
    __builtin_amdgcn_s_setprio(1);
    #pragma unroll
    for (int ks = 0; ks < 2; ks++)
      #pragma unroll
      for (int m = 0; m < 2; m++)
        #pragma unroll
        for (int n = 0; n < 4; n++)
          acc[m][n] = __builtin_amdgcn_mfma_f32_16x16x32_bf16(
              afr[m][ks], bfr[n][ks], acc[m][n], 0, 0, 0);
    __builtin_amdgcn_s_setprio(0);

    // SUB2: A frags m=2..3, then 16 MFMA (no barrier: same tile, no hazard)
    #pragma unroll
    for (int m = 0; m < 2; m++)
      #pragma unroll
      for (int ks = 0; ks < 2; ks++)
        af2[m][ks] = *(const bf16x8*)(lds + aRd[m + 2][ks]);
    __builtin_amdgcn_s_setprio(1);
    #pragma unroll
    for (int ks = 0; ks < 2; ks++)
      #pragma unroll
      for (int m = 0; m < 2; m++)
        #pragma unroll
        for (int n = 0; n < 4; n++)
          acc[m + 2][n] = __builtin_amdgcn_mfma_f32_16x16x32_bf16(
              af2[m][ks], bfr[n][ks], acc[m + 2][n], 0, 0, 0);
    __builtin_amdgcn_s_setprio(0);
  }
#undef STAGE

  // ---- epilogue: D row=(lane>>4)*4+r (A rows), col=lane&15 (B rows) ----
  #pragma unroll
  for (int m = 0; m < 4; m++) {
    #pragma unroll
    for (int n = 0; n < 4; n++) {
      int gcol = n0 + wc * 64 + n * 16 + c;
      float bv = bias[gcol];
      float val[4];
      #pragma unroll
      for (int r = 0; r < 4; r++) val[r] = acc[m][n][r] + bv;
      if (MODE == 0) {
        int s = n0 >> 11;                // 0:q 1:k 2:v (uniform per block)
        int rem = gcol & 2047;
        int h = rem >> 7, d = rem & 127;
        int growb = m0 + wr * 64 + m * 16;
        int b0 = growb >> 11;            // uniform within the 16-row frag
        if (s == 2) {
          // V direct-transposed: Vt[(b*16+h)*128 + d][t], 4 consecutive t
          size_t vb = (((size_t)(b0 * NHEADS + h)) * DHEAD + d) * TDIM;
          int t0 = (growb & (TDIM - 1)) + g * 4;
          ushort4 pk;
          pk.x = f2bf(val[0]); pk.y = f2bf(val[1]);
          pk.z = f2bf(val[2]); pk.w = f2bf(val[3]);
          *(ushort4*)(v_out + vb + t0) = pk;
        } else {
          // fused RoPE: pairs (d, d^1) live in lanes (c, c^1)
          size_t hb = (((size_t)(b0 * NHEADS + h)) * TDIM) * DHEAD + d;
          int mf = gcol & 63;            // freq index = d & 63
          float sgn = (c & 1) ? 1.0f : -1.0f;
          u16* dst = (s == 0) ? q_out : k_out;
          float qs = (s == 0) ? 0.08838834764831845f : 1.0f;
          #pragma unroll
          for (int r = 0; r < 4; r++) {
            float part = __shfl_xor(val[r], 1, 64);
            int t = (growb + g * 4 + r) & (TDIM - 1);
            float cs = ct[t * 64 + mf], sn = st[t * 64 + mf];
            float rot = (val[r] * cs + sgn * part * sn) * qs;
            dst[hb + (size_t)t * DHEAD] = f2bf(rot);
          }
        }
      } else {
        #pragma unroll
        for (int r = 0; r < 4; r++) {
          int grow = m0 + wr * 64 + m * 16 + g * 4 + r;
          f_out[(size_t)grow * DMODEL + gcol] = val[r];
        }
      }
    }
  }
}

// ---------------- Flash attention (causal), 4 waves x 16 q-rows -----------
// R16-proven: K and V both double-buffered; tile t+1 (K+V) staged at
// iteration TOP into buffers [cur^1]; per-iter sync = 1 lgkmcnt + 1 vmcnt +
// 1 barrier. Causal-paired q-tiles {i, 31-i}. LDS 72KB -> 2 blocks/CU.
// Q,K: [BH][T][128] bf16 (Q pre-scaled); Vt: [BH][128][T]; Yattn: [B][T][HD]
__global__ __launch_bounds__(256) void attn_kernel(
    const u16* __restrict__ Q, const u16* __restrict__ K,
    const u16* __restrict__ Vt, u16* __restrict__ Yattn) {
  __shared__ u16 Ks[2][64 * 128]; // [kv][d], swizzle chunk^=(row&7) (2x16KB)
  __shared__ u16 Vs[2][128 * 64]; // [d][kv], swizzle chunk^=(row&7) (2x16KB)
  __shared__ u16 Ps[4][16 * 64];  // per-wave P tile, swizzled (8 KB)
  const int tid = threadIdx.x, lane = tid & 63, w = tid >> 6;
  const int g = lane >> 4, c = lane & 15;
  const int bh = blockIdx.y, b = bh >> 4, h = bh & 15;
  const u16* Qp = Q + (size_t)bh * TDIM * DHEAD;
  const u16* Kp = K + (size_t)bh * TDIM * DHEAD;
  const u16* Vp = Vt + (size_t)bh * DHEAD * TDIM;
  const f32x4 zero = {0.f, 0.f, 0.f, 0.f};

#define STAGE_K(kv0, buf)                                                    \
  {                                                                          \
    _Pragma("unroll") for (int p_ = 0; p_ < 4; p_++) {                       \
      int off = p_ * 4096 + tid * 16;                                        \
      int kr = off >> 8, kc4 = (off & 255) >> 4;                             \
      GLOAD16((const char*)Kp + (size_t)((kv0) + kr) * 256 +                 \
                  ((kc4 ^ (kr & 7)) << 4),                                   \
              (char*)Ks[buf] + off);                                         \
    }                                                                        \
  }
#define STAGE_V(kv0, buf)                                                    \
  {                                                                          \
    _Pragma("unroll") for (int p_ = 0; p_ < 4; p_++) {                       \
      int off = p_ * 4096 + tid * 16;                                        \
      int vr = off >> 7, vc4 = (off & 127) >> 4;                             \
      GLOAD16((const char*)Vp + (size_t)vr * (TDIM * 2) + (size_t)(kv0) * 2 +\
                  ((vc4 ^ (vr & 7)) << 4),                                   \
              (char*)Vs[buf] + off);                                         \
    }                                                                        \
  }

  for (int half = 0; half < 2; half++) {
    const int qt = half ? (31 - (int)blockIdx.x) : (int)blockIdx.x;
    const int qb = qt * 64 + w * 16;

    bf16x8 qf[4];
    #pragma unroll
    for (int kc = 0; kc < 4; kc++)
      qf[kc] = *(const bf16x8*)(Qp + (size_t)(qb + c) * DHEAD + kc * 32 + g * 8);

    f32x4 po[8];
    #pragma unroll
    for (int df = 0; df < 8; df++) po[df] = zero;
    float mrun[4], lrun[4];
    #pragma unroll
    for (int r = 0; r < 4; r++) { mrun[r] = -1e30f; lrun[r] = 0.f; }

    const int nt = qt + 1;

    // ---- prologue: stage tile 0 (K+V) into buf 0; wait landed ----
    STAGE_K(0, 0);
    STAGE_V(0, 0);
    asm volatile("s_waitcnt vmcnt(0)" ::: "memory");
    __builtin_amdgcn_s_barrier();
    __builtin_amdgcn_sched_barrier(0);

    int cur = 0;
    for (int t = 0; t < nt; t++) {
      const int kv0 = t * 64;
      const bool more = (t + 1 < nt);

      // ---- issue full tile t+1 prefetch (K then V) into other buffers ----
      if (more) {
        STAGE_K(kv0 + 64, cur ^ 1);
        STAGE_V(kv0 + 64, cur ^ 1);
      }

      // ---- S = Q @ K^T (16 x 64 per wave) reads Ks[cur] ----
      const u16* KsC = Ks[cur];
      const u16* VsC = Vs[cur];
      f32x4 sa[4];
      #pragma unroll
      for (int n = 0; n < 4; n++) sa[n] = zero;
      __builtin_amdgcn_s_setprio(1);
      #pragma unroll
      for (int n = 0; n < 4; n++) {
        int krow = n * 16 + c;
        #pragma unroll
        for (int kc = 0; kc < 4; kc++) {
          int kb = (kc * 32 + g * 8) * 2;
          bf16x8 kf = *(const bf16x8*)((const char*)KsC + krow * 256 +
                                       (kb ^ ((krow & 7) << 4)));
          sa[n] = __builtin_amdgcn_mfma_f32_16x16x32_bf16(qf[kc], kf, sa[n], 0, 0, 0);
        }
      }
      __builtin_amdgcn_s_setprio(0);

      // ---- causal mask (only tiles straddling the diagonal) ----
      if (kv0 + 63 > qb) {
        #pragma unroll
        for (int n = 0; n < 4; n++) {
          int col = kv0 + n * 16 + c;
          #pragma unroll
          for (int r = 0; r < 4; r++) {
            int qrow = qb + g * 4 + r;
            if (col > qrow) sa[n][r] = -1e30f;
          }
        }
      }

      // ---- online softmax (rows g*4+r, cols n*16+c) ----
      float pvals[4][4];
      #pragma unroll
      for (int r = 0; r < 4; r++) {
        float vmax = fmaxf(fmaxf(sa[0][r], sa[1][r]), fmaxf(sa[2][r], sa[3][r]));
        #pragma unroll
        for (int d = 1; d < 16; d <<= 1) vmax = fmaxf(vmax, __shfl_xor(vmax, d, 64));
        float mnew = fmaxf(mrun[r], vmax);
        float scale = __expf(mrun[r] - mnew);
        float rs = 0.f;
        #pragma unroll
        for (int n = 0; n < 4; n++) {
          float p = __expf(sa[n][r] - mnew);
          pvals[r][n] = p;
          rs += p;
        }
        #pragma unroll
        for (int d = 1; d < 16; d <<= 1) rs += __shfl_xor(rs, d, 64);
        lrun[r] = lrun[r] * scale + rs;
        mrun[r] = mnew;
        #pragma unroll
        for (int df = 0; df < 8; df++) po[df][r] *= scale;
      }

      // ---- P -> LDS (per-wave, swizzled), then PV reads Vs[cur] ----
      char* Pw = (char*)&Ps[w][0];
      #pragma unroll
      for (int r = 0; r < 4; r++) {
        int ri = g * 4 + r;
        #pragma unroll
        for (int n = 0; n < 4; n++) {
          int colb = (n * 16 + c) * 2;
          *(u16*)(Pw + ri * 128 + (colb ^ ((ri & 7) << 4))) = f2bf(pvals[r][n]);
        }
      }
      bf16x8 pa[2];
      #pragma unroll
      for (int kc2 = 0; kc2 < 2; kc2++) {
        int pb = (kc2 * 32 + g * 8) * 2;
        pa[kc2] = *(const bf16x8*)(Pw + c * 128 + (pb ^ ((c & 7) << 4)));
      }
      __builtin_amdgcn_s_setprio(1);
      #pragma unroll
      for (int df = 0; df < 8; df++) {
        #pragma unroll
        for (int kc2 = 0; kc2 < 2; kc2++) {
          int vrow = df * 16 + c;
          int vb = (kc2 * 32 + g * 8) * 2;
          bf16x8 vf = *(const bf16x8*)((const char*)VsC + vrow * 128 +
                                       (vb ^ ((vrow & 7) << 4)));
          po[df] = __builtin_amdgcn_mfma_f32_16x16x32_bf16(pa[kc2], vf, po[df], 0, 0, 0);
        }
      }
      __builtin_amdgcn_s_setprio(0);

      // ---- single sync point per iteration ----
      asm volatile("s_waitcnt lgkmcnt(0)" ::: "memory"); // own LDS reads done
      if (more) {
        asm volatile("s_waitcnt vmcnt(0)" ::: "memory"); // own t+1 loads landed
      }
      __builtin_amdgcn_s_barrier();  // all waves: reads retired, writes visible
      __builtin_amdgcn_sched_barrier(0);
      cur ^= 1;
    }

    float inv[4];
    #pragma unroll
    for (int r = 0; r < 4; r++) inv[r] = 1.0f / lrun[r];
    #pragma unroll
    for (int df = 0; df < 8; df++) {
      #pragma unroll
      for (int r = 0; r < 4; r++) {
        int trow = qb + g * 4 + r;
        int col = h * DHEAD + df * 16 + c;
        Yattn[((size_t)b * TDIM + trow) * DMODEL + col] = f2bf(po[df][r] * inv[r]);
      }
    }
    // half-boundary: last iter ended with lgkmcnt(0)+barrier and no loads
    // outstanding -> next half's prologue staging (into buf0) is safe.
  }
#undef STAGE_K
#undef STAGE_V
}

extern "C" void kernel_launch(void* const* d_in, const int* in_sizes, int n_in,
                              void* d_out, int out_size, void* d_ws, size_t ws_size,
                              hipStream_t stream) {
  const float* x    = (const float*)d_in[0];
  // d_in[1] = mask (exact causal triu; implemented analytically)
  const float* Wqkv = (const float*)d_in[2];
  const float* bqkv = (const float*)d_in[3];
  const float* Wo   = (const float*)d_in[4];
  const float* bo   = (const float*)d_in[5];
  float* out = (float*)d_out;

  char* ws = (char*)d_ws;
  size_t o = 0;
  u16* xb    = (u16*)(ws + o); o += (size_t)NTOK * DMODEL * 2;     // 16.8 MB
  u16* Wqkvt = (u16*)(ws + o); o += (size_t)NQKV * DMODEL * 2;     // 25.2 MB
  u16* Wot   = (u16*)(ws + o); o += (size_t)DMODEL * DMODEL * 2;   // 8.4 MB
  u16* Qb    = (u16*)(ws + o); o += (size_t)BHTOT * TDIM * DHEAD * 2;
  u16* Kb    = (u16*)(ws + o); o += (size_t)BHTOT * TDIM * DHEAD * 2;
  u16* Vt    = (u16*)(ws + o); o += (size_t)BHTOT * TDIM * DHEAD * 2;
  float* ct  = (float*)(ws + o); o += (size_t)TDIM * 64 * 4;
  float* st  = (float*)(ws + o); o += (size_t)TDIM * 64 * 4;
  u16* Yattn = xb;    // alias: xb dead after GEMM1

  // one fused prep dispatch: rope table + x convert + both W transposes
  prep_kernel<<<12800, 256, 0, stream>>>(x, xb, Wqkv, Wqkvt, Wo, Wot, ct, st);

  // BM=BN=128 single-buffer m97-style: grid1 = 32x48 = 1536 blocks (4/CU);
  // RoPE fused on Q/K, V written direct-transposed (no vtrans kernel).
  gemm_bt_kernel<0><<<dim3(NTOK / 128, NQKV / 128), 256, 0, stream>>>(
      xb, Wqkvt, bqkv, Qb, Kb, Vt, nullptr, ct, st, DMODEL);

  // causal-paired q-tiles: grid.x = 16 pairs, each block does {i, 31-i}
  attn_kernel<<<dim3(16, BHTOT), 256, 0, stream>>>(Qb, Kb, Vt, Yattn);

  // grid2 = 32x16 = 512 blocks
  gemm_bt_kernel<1><<<dim3(NTOK / 128, DMODEL / 128), 256, 0, stream>>>(
      Yattn, Wot, bo, nullptr, nullptr, nullptr, out, nullptr, nullptr, DMODEL);
}

// Round 20
// 257.387 us; speedup vs baseline: 1.0817x; 1.0581x over previous
//
#include <hip/hip_runtime.h>
#include <stdint.h>

#define TDIM 2048
#define DMODEL 2048
#define NHEADS 16
#define DHEAD 128
#define NBATCH 2
#define NTOK (NBATCH * TDIM)   // 4096
#define NQKV (3 * DMODEL)      // 6144
#define BHTOT (NBATCH * NHEADS) // 32

typedef unsigned short u16;
typedef __attribute__((ext_vector_type(8))) short bf16x8;
typedef __attribute__((ext_vector_type(4))) float f32x4;
typedef __attribute__((ext_vector_type(4))) int i32x4;

__device__ __forceinline__ u16 f2bf(float f) {
  union { float f; uint32_t u; } v; v.f = f;
  uint32_t u = v.u + 0x7fffu + ((v.u >> 16) & 1u);
  return (u16)(u >> 16);
}
__device__ __forceinline__ float bf2f(u16 h) {
  union { uint32_t u; float f; } v; v.u = ((uint32_t)h) << 16;
  return v.f;
}

#define GLOAD16(g, l)                                                        \
  __builtin_amdgcn_global_load_lds(                                          \
      (const __attribute__((address_space(1))) void*)(g),                    \
      (__attribute__((address_space(3))) void*)(l), 16, 0, 0)

// ---------------- merged prep: rope table + convert + 2 transposes --------
__device__ __forceinline__ void tc_tile(const float* __restrict__ in,
                                        u16* __restrict__ out, int K, int N,
                                        int n0, int k0, int t) {
  __shared__ u16 tile[64][65];
  #pragma unroll
  for (int q = 0; q < 4; q++) {
    int idx = q * 1024 + t * 4;        // 0..4095 over the 64x64 tile
    int k = idx >> 6, n = idx & 63;
    float4 v = *(const float4*)&in[(size_t)(k0 + k) * N + n0 + n];
    tile[k][n]     = f2bf(v.x);
    tile[k][n + 1] = f2bf(v.y);
    tile[k][n + 2] = f2bf(v.z);
    tile[k][n + 3] = f2bf(v.w);
  }
  __syncthreads();
  #pragma unroll
  for (int q = 0; q < 4; q++) {
    int n = (t >> 4) + q * 16;         // 0..63
    int k4 = (t & 15) * 4;             // 0,4,...,60
    ushort4 o;
    o.x = tile[k4][n];     o.y = tile[k4 + 1][n];
    o.z = tile[k4 + 2][n]; o.w = tile[k4 + 3][n];
    *(ushort4*)&out[(size_t)(n0 + n) * K + k0 + k4] = o;
  }
}

__global__ __launch_bounds__(256) void prep_kernel(
    const float* __restrict__ x, u16* __restrict__ xb,
    const float* __restrict__ Wqkv, u16* __restrict__ Wqkvt,
    const float* __restrict__ Wo, u16* __restrict__ Wot,
    float* __restrict__ ct, float* __restrict__ st) {
  const int bid = blockIdx.x;
  const int t = threadIdx.x;
  if (bid < 512) {
    int idx = bid * 256 + t;           // TDIM*64 total
    int tt = idx >> 6, m = idx & 63;
    float inv = expf(-(float)m * (9.210340371976184f / 64.0f));
    float ang = (float)tt * inv;
    ct[idx] = cosf(ang);
    st[idx] = sinf(ang);
  } else if (bid < 8704) {
    int i = (bid - 512) * 256 + t;     // NTOK*DMODEL/4 elements
    float4 v = ((const float4*)x)[i];
    ushort4 o;
    o.x = f2bf(v.x); o.y = f2bf(v.y); o.z = f2bf(v.z); o.w = f2bf(v.w);
    ((ushort4*)xb)[i] = o;
  } else if (bid < 11776) {
    int tb = bid - 8704;               // Wqkv: 96 x-tiles, 32 y-tiles
    int bx = tb % 96, by = tb / 96;
    tc_tile(Wqkv, Wqkvt, DMODEL, NQKV, bx * 64, by * 64, t);
  } else {
    int tb = bid - 11776;              // Wo: 32 x 32 tiles
    int bx = tb & 31, by = tb >> 5;
    tc_tile(Wo, Wot, DMODEL, DMODEL, bx * 64, by * 64, t);
  }
}

// ---------------- m97-style GEMM: A (M,K) @ Bt (N,K), bf16 ----------------
// R19-proven: 128x128, BK=64, 4 waves, SINGLE-buffer 32KB LDS -> 4-5
// blocks/CU; cross-block TLP hides the per-tile vmcnt(0) drain (m114).
// MODE 0: + bias, fused RoPE on Q/K; V direct-transposed to Vt[b][h][d][t].
// MODE 1: + bias -> fp32 row-major out (N=DMODEL)
template <int MODE>
__global__ __launch_bounds__(256) void gemm_bt_kernel(
    const u16* __restrict__ A, const u16* __restrict__ Bt,
    const float* __restrict__ bias,
    u16* __restrict__ q_out, u16* __restrict__ k_out, u16* __restrict__ v_out,
    float* __restrict__ f_out,
    const float* __restrict__ ct, const float* __restrict__ st, int K) {
  __shared__ __attribute__((aligned(128))) char lds[32768];
  const int tid = threadIdx.x;
  const int lane = tid & 63, w = tid >> 6;
  const int wr = w >> 1, wc = w & 1;          // wave grid 2 x 2
  const int g = lane >> 4, c = lane & 15;
  const int m0 = blockIdx.x * 128, n0 = blockIdx.y * 128;
  const size_t rowb = (size_t)K * 2;
  const int NKT = K >> 6;

  const char* sSrc[8]; int sDst[8];
  #pragma unroll
  for (int p = 0; p < 4; p++) {
    int o = p * 4096 + tid * 16;
    int row = o >> 7, j = (o >> 4) & 7;
    sSrc[p] = (const char*)A + (size_t)(m0 + row) * rowb + ((j ^ (row & 7)) << 4);
    sDst[p] = o;
    sSrc[4 + p] = (const char*)Bt + (size_t)(n0 + row) * rowb +
                  ((j ^ (row & 7)) << 4);
    sDst[4 + p] = 16384 + o;
  }

#define STAGE(kt)                                                            \
  {                                                                          \
    const size_t kb_ = (size_t)(kt) * 128;                                   \
    _Pragma("unroll") for (int p_ = 0; p_ < 8; p_++)                         \
        GLOAD16(sSrc[p_] + kb_, lds + sDst[p_]);                             \
  }

  int aRd[4][2], bRd[4][2];
  #pragma unroll
  for (int m = 0; m < 4; m++) {
    #pragma unroll
    for (int ks = 0; ks < 2; ks++) {
      int arow = wr * 64 + m * 16 + c;
      aRd[m][ks] = arow * 128 + (((ks * 4 + g) ^ (c & 7)) << 4);
      int brow = wc * 64 + m * 16 + c;
      bRd[m][ks] = 16384 + brow * 128 + (((ks * 4 + g) ^ (c & 7)) << 4);
    }
  }

  const f32x4 zero = {0.f, 0.f, 0.f, 0.f};
  f32x4 acc[4][4];
  #pragma unroll
  for (int m = 0; m < 4; m++)
    #pragma unroll
    for (int n = 0; n < 4; n++) acc[m][n] = zero;

  for (int kt = 0; kt < NKT; kt++) {
    if (kt) {
      asm volatile("s_waitcnt lgkmcnt(0)" ::: "memory");
      __builtin_amdgcn_s_barrier();
      __builtin_amdgcn_sched_barrier(0);
    }
    STAGE(kt);
    asm volatile("s_waitcnt vmcnt(0)" ::: "memory");
    __builtin_amdgcn_s_barrier();
    __builtin_amdgcn_sched_barrier(0);

    bf16x8 bfr[4][2], afr[2][2], af2[2][2];
    #pragma unroll
    for (int n = 0; n < 4; n++)
      #pragma unroll
      for (int ks = 0; ks < 2; ks++)
        bfr[n][ks] = *(const bf16x8*)(lds + bRd[n][ks]);
    #pragma unroll
    for (int m = 0; m < 2; m++)
      #pragma unroll
      for (int ks = 0; ks < 2; ks++)
        afr[m][ks] = *(const bf16x8*)(lds + aRd[m][ks]);
    __builtin_amdgcn_s_setprio(1);
    #pragma unroll
    for (int ks = 0; ks < 2; ks++)
      #pragma unroll
      for (int m = 0; m < 2; m++)
        #pragma unroll
        for (int n = 0; n < 4; n++)
          acc[m][n] = __builtin_amdgcn_mfma_f32_16x16x32_bf16(
              afr[m][ks], bfr[n][ks], acc[m][n], 0, 0, 0);
    __builtin_amdgcn_s_setprio(0);

    #pragma unroll
    for (int m = 0; m < 2; m++)
      #pragma unroll
      for (int ks = 0; ks < 2; ks++)
        af2[m][ks] = *(const bf16x8*)(lds + aRd[m + 2][ks]);
    __builtin_amdgcn_s_setprio(1);
    #pragma unroll
    for (int ks = 0; ks < 2; ks++)
      #pragma unroll
      for (int m = 0; m < 2; m++)
        #pragma unroll
        for (int n = 0; n < 4; n++)
          acc[m + 2][n] = __builtin_amdgcn_mfma_f32_16x16x32_bf16(
              af2[m][ks], bfr[n][ks], acc[m + 2][n], 0, 0, 0);
    __builtin_amdgcn_s_setprio(0);
  }
#undef STAGE

  // ---- epilogue: D row=(lane>>4)*4+r (A rows), col=lane&15 (B rows) ----
  #pragma unroll
  for (int m = 0; m < 4; m++) {
    #pragma unroll
    for (int n = 0; n < 4; n++) {
      int gcol = n0 + wc * 64 + n * 16 + c;
      float bv = bias[gcol];
      float val[4];
      #pragma unroll
      for (int r = 0; r < 4; r++) val[r] = acc[m][n][r] + bv;
      if (MODE == 0) {
        int s = n0 >> 11;                // 0:q 1:k 2:v (uniform per block)
        int rem = gcol & 2047;
        int h = rem >> 7, d = rem & 127;
        int growb = m0 + wr * 64 + m * 16;
        int b0 = growb >> 11;            // uniform within the 16-row frag
        if (s == 2) {
          size_t vb = (((size_t)(b0 * NHEADS + h)) * DHEAD + d) * TDIM;
          int t0 = (growb & (TDIM - 1)) + g * 4;
          ushort4 pk;
          pk.x = f2bf(val[0]); pk.y = f2bf(val[1]);
          pk.z = f2bf(val[2]); pk.w = f2bf(val[3]);
          *(ushort4*)(v_out + vb + t0) = pk;
        } else {
          size_t hb = (((size_t)(b0 * NHEADS + h)) * TDIM) * DHEAD + d;
          int mf = gcol & 63;            // freq index = d & 63
          float sgn = (c & 1) ? 1.0f : -1.0f;
          u16* dst = (s == 0) ? q_out : k_out;
          float qs = (s == 0) ? 0.08838834764831845f : 1.0f;
          #pragma unroll
          for (int r = 0; r < 4; r++) {
            float part = __shfl_xor(val[r], 1, 64);
            int t = (growb + g * 4 + r) & (TDIM - 1);
            float cs = ct[t * 64 + mf], sn = st[t * 64 + mf];
            float rot = (val[r] * cs + sgn * part * sn) * qs;
            dst[hb + (size_t)t * DHEAD] = f2bf(rot);
          }
        }
      } else {
        #pragma unroll
        for (int r = 0; r < 4; r++) {
          int grow = m0 + wr * 64 + m * 16 + g * 4 + r;
          f_out[(size_t)grow * DMODEL + gcol] = val[r];
        }
      }
    }
  }
}

// ---------------- Flash attention (causal), 4 waves x 16 q-rows -----------
// R16 sync structure + SWAPPED QK^T (T12 mechanism): sa[n] = mfma(kf, qf)
// gives D[row=kv_local][col=q] -> lane (g,c) holds S[q=c][kv=16n+4g+r]:
// each lane owns ONE q-row. Softmax: local max/sum over 16 regs + 2
// shfl_xor (d=16,32) each (was 2x 4-deep trees per r = 32 cross-lane ops);
// scale broadcast to po rows (q=g*4+r, owner lane q<16) via 4 shuffles.
// P_lds roundtrip kept: write row=c, col=16n+4g+r; pa reads unchanged
// (PV A-row = q = c). K/V double-buffered, 1 barrier/iter, 72KB LDS.
// Q,K: [BH][T][128] bf16 (Q pre-scaled); Vt: [BH][128][T]; Yattn: [B][T][HD]
__global__ __launch_bounds__(256) void attn_kernel(
    const u16* __restrict__ Q, const u16* __restrict__ K,
    const u16* __restrict__ Vt, u16* __restrict__ Yattn) {
  __shared__ u16 Ks[2][64 * 128]; // [kv][d], swizzle chunk^=(row&7) (2x16KB)
  __shared__ u16 Vs[2][128 * 64]; // [d][kv], swizzle chunk^=(row&7) (2x16KB)
  __shared__ u16 Ps[4][16 * 64];  // per-wave P tile, swizzled (8 KB)
  const int tid = threadIdx.x, lane = tid & 63, w = tid >> 6;
  const int g = lane >> 4, c = lane & 15;
  const int bh = blockIdx.y, b = bh >> 4, h = bh & 15;
  const u16* Qp = Q + (size_t)bh * TDIM * DHEAD;
  const u16* Kp = K + (size_t)bh * TDIM * DHEAD;
  const u16* Vp = Vt + (size_t)bh * DHEAD * TDIM;
  const f32x4 zero = {0.f, 0.f, 0.f, 0.f};

#define STAGE_K(kv0, buf)                                                    \
  {                                                                          \
    _Pragma("unroll") for (int p_ = 0; p_ < 4; p_++) {                       \
      int off = p_ * 4096 + tid * 16;                                        \
      int kr = off >> 8, kc4 = (off & 255) >> 4;                             \
      GLOAD16((const char*)Kp + (size_t)((kv0) + kr) * 256 +                 \
                  ((kc4 ^ (kr & 7)) << 4),                                   \
              (char*)Ks[buf] + off);                                         \
    }                                                                        \
  }
#define STAGE_V(kv0, buf)                                                    \
  {                                                                          \
    _Pragma("unroll") for (int p_ = 0; p_ < 4; p_++) {                       \
      int off = p_ * 4096 + tid * 16;                                        \
      int vr = off >> 7, vc4 = (off & 127) >> 4;                             \
      GLOAD16((const char*)Vp + (size_t)vr * (TDIM * 2) + (size_t)(kv0) * 2 +\
                  ((vc4 ^ (vr & 7)) << 4),                                   \
              (char*)Vs[buf] + off);                                         \
    }                                                                        \
  }

  for (int half = 0; half < 2; half++) {
    const int qt = half ? (31 - (int)blockIdx.x) : (int)blockIdx.x;
    const int qb = qt * 64 + w * 16;
    const int qrow = qb + c;           // this lane's q-row (softmax owner: c)

    bf16x8 qf[4];
    #pragma unroll
    for (int kc = 0; kc < 4; kc++)
      qf[kc] = *(const bf16x8*)(Qp + (size_t)(qb + c) * DHEAD + kc * 32 + g * 8);

    f32x4 po[8];
    #pragma unroll
    for (int df = 0; df < 8; df++) po[df] = zero;
    float mrun = -1e30f, lrun = 0.f;   // per-lane: own row q=c

    const int nt = qt + 1;

    // ---- prologue: stage tile 0 (K+V) into buf 0; wait landed ----
    STAGE_K(0, 0);
    STAGE_V(0, 0);
    asm volatile("s_waitcnt vmcnt(0)" ::: "memory");
    __builtin_amdgcn_s_barrier();
    __builtin_amdgcn_sched_barrier(0);

    int cur = 0;
    for (int t = 0; t < nt; t++) {
      const int kv0 = t * 64;
      const bool more = (t + 1 < nt);

      // ---- issue full tile t+1 prefetch (K then V) into other buffers ----
      if (more) {
        STAGE_K(kv0 + 64, cur ^ 1);
        STAGE_V(kv0 + 64, cur ^ 1);
      }

      // ---- S^T = K @ Q^T (swapped operands; fragments unchanged) ----
      // sa[n][r] = S[q = c][kv = kv0 + 16n + 4g + r]
      const u16* KsC = Ks[cur];
      const u16* VsC = Vs[cur];
      f32x4 sa[4];
      #pragma unroll
      for (int n = 0; n < 4; n++) sa[n] = zero;
      __builtin_amdgcn_s_setprio(1);
      #pragma unroll
      for (int n = 0; n < 4; n++) {
        int krow = n * 16 + c;
        #pragma unroll
        for (int kc = 0; kc < 4; kc++) {
          int kb = (kc * 32 + g * 8) * 2;
          bf16x8 kf = *(const bf16x8*)((const char*)KsC + krow * 256 +
                                       (kb ^ ((krow & 7) << 4)));
          sa[n] = __builtin_amdgcn_mfma_f32_16x16x32_bf16(kf, qf[kc], sa[n], 0, 0, 0);
        }
      }
      __builtin_amdgcn_s_setprio(0);

      // ---- causal mask (per-register kv, per-lane q) ----
      if (kv0 + 63 > qb) {
        #pragma unroll
        for (int n = 0; n < 4; n++) {
          #pragma unroll
          for (int r = 0; r < 4; r++) {
            int kvv = kv0 + n * 16 + g * 4 + r;
            if (kvv > qrow) sa[n][r] = -1e30f;
          }
        }
      }

      // ---- online softmax: lane owns row q=c entirely ----
      float vmax = mrun;
      #pragma unroll
      for (int n = 0; n < 4; n++)
        #pragma unroll
        for (int r = 0; r < 4; r++) vmax = fmaxf(vmax, sa[n][r]);
      vmax = fmaxf(vmax, __shfl_xor(vmax, 16, 64));
      vmax = fmaxf(vmax, __shfl_xor(vmax, 32, 64));
      float mnew = vmax;                       // includes mrun
      float scale = __expf(mrun - mnew);
      float pv16[4][4];
      float rs = 0.f;
      #pragma unroll
      for (int n = 0; n < 4; n++)
        #pragma unroll
        for (int r = 0; r < 4; r++) {
          float p = __expf(sa[n][r] - mnew);
          pv16[n][r] = p;
          rs += p;
        }
      rs += __shfl_xor(rs, 16, 64);
      rs += __shfl_xor(rs, 32, 64);
      lrun = lrun * scale + rs;
      mrun = mnew;
      // broadcast scale to po rows (row q' = g*4+r, owner lane q' < 16)
      float sc[4];
      #pragma unroll
      for (int r = 0; r < 4; r++) sc[r] = __shfl(scale, g * 4 + r, 64);
      #pragma unroll
      for (int df = 0; df < 8; df++)
        #pragma unroll
        for (int r = 0; r < 4; r++) po[df][r] *= sc[r];

      // ---- P -> LDS (row = c, col = 16n+4g+r), then PV reads Vs[cur] ----
      char* Pw = (char*)&Ps[w][0];
      #pragma unroll
      for (int n = 0; n < 4; n++) {
        #pragma unroll
        for (int r = 0; r < 4; r++) {
          int colb = (n * 16 + g * 4 + r) * 2;
          *(u16*)(Pw + c * 128 + (colb ^ ((c & 7) << 4))) = f2bf(pv16[n][r]);
        }
      }
      bf16x8 pa[2];
      #pragma unroll
      for (int kc2 = 0; kc2 < 2; kc2++) {
        int pb = (kc2 * 32 + g * 8) * 2;
        pa[kc2] = *(const bf16x8*)(Pw + c * 128 + (pb ^ ((c & 7) << 4)));
      }
      __builtin_amdgcn_s_setprio(1);
      #pragma unroll
      for (int df = 0; df < 8; df++) {
        #pragma unroll
        for (int kc2 = 0; kc2 < 2; kc2++) {
          int vrow = df * 16 + c;
          int vb = (kc2 * 32 + g * 8) * 2;
          bf16x8 vf = *(const bf16x8*)((const char*)VsC + vrow * 128 +
                                       (vb ^ ((vrow & 7) << 4)));
          po[df] = __builtin_amdgcn_mfma_f32_16x16x32_bf16(pa[kc2], vf, po[df], 0, 0, 0);
        }
      }
      __builtin_amdgcn_s_setprio(0);

      // ---- single sync point per iteration ----
      asm volatile("s_waitcnt lgkmcnt(0)" ::: "memory"); // own LDS reads done
      if (more) {
        asm volatile("s_waitcnt vmcnt(0)" ::: "memory"); // own t+1 loads landed
      }
      __builtin_amdgcn_s_barrier();  // all waves: reads retired, writes visible
      __builtin_amdgcn_sched_barrier(0);
      cur ^= 1;
    }

    // final normalize: inv for row q' = g*4+r broadcast from owner lane
    float rcp = 1.0f / lrun;
    float inv[4];
    #pragma unroll
    for (int r = 0; r < 4; r++) inv[r] = __shfl(rcp, g * 4 + r, 64);
    #pragma unroll
    for (int df = 0; df < 8; df++) {
      #pragma unroll
      for (int r = 0; r < 4; r++) {
        int trow = qb + g * 4 + r;
        int col = h * DHEAD + df * 16 + c;
        Yattn[((size_t)b * TDIM + trow) * DMODEL + col] = f2bf(po[df][r] * inv[r]);
      }
    }
    // half-boundary: last iter ended with lgkmcnt(0)+barrier and no loads
    // outstanding -> next half's prologue staging (into buf0) is safe.
  }
#undef STAGE_K
#undef STAGE_V
}

extern "C" void kernel_launch(void* const* d_in, const int* in_sizes, int n_in,
                              void* d_out, int out_size, void* d_ws, size_t ws_size,
                              hipStream_t stream) {
  const float* x    = (const float*)d_in[0];
  // d_in[1] = mask (exact causal triu; implemented analytically)
  const float* Wqkv = (const float*)d_in[2];
  const float* bqkv = (const float*)d_in[3];
  const float* Wo   = (const float*)d_in[4];
  const float* bo   = (const float*)d_in[5];
  float* out = (float*)d_out;

  char* ws = (char*)d_ws;
  size_t o = 0;
  u16* xb    = (u16*)(ws + o); o += (size_t)NTOK * DMODEL * 2;     // 16.8 MB
  u16* Wqkvt = (u16*)(ws + o); o += (size_t)NQKV * DMODEL * 2;     // 25.2 MB
  u16* Wot   = (u16*)(ws + o); o += (size_t)DMODEL * DMODEL * 2;   // 8.4 MB
  u16* Qb    = (u16*)(ws + o); o += (size_t)BHTOT * TDIM * DHEAD * 2;
  u16* Kb    = (u16*)(ws + o); o += (size_t)BHTOT * TDIM * DHEAD * 2;
  u16* Vt    = (u16*)(ws + o); o += (size_t)BHTOT * TDIM * DHEAD * 2;
  float* ct  = (float*)(ws + o); o += (size_t)TDIM * 64 * 4;
  float* st  = (float*)(ws + o); o += (size_t)TDIM * 64 * 4;
  u16* Yattn = xb;    // alias: xb dead after GEMM1

  // one fused prep dispatch: rope table + x convert + both W transposes
  prep_kernel<<<12800, 256, 0, stream>>>(x, xb, Wqkv, Wqkvt, Wo, Wot, ct, st);

  // BM=BN=128 single-buffer m97-style: grid1 = 32x48 = 1536 blocks (4/CU);
  // RoPE fused on Q/K, V written direct-transposed (no vtrans kernel).
  gemm_bt_kernel<0><<<dim3(NTOK / 128, NQKV / 128), 256, 0, stream>>>(
      xb, Wqkvt, bqkv, Qb, Kb, Vt, nullptr, ct, st, DMODEL);

  // causal-paired q-tiles: grid.x = 16 pairs, each block does {i, 31-i}
  attn_kernel<<<dim3(16, BHTOT), 256, 0, stream>>>(Qb, Kb, Vt, Yattn);

  // grid2 = 32x16 = 512 blocks
  gemm_bt_kernel<1><<<dim3(NTOK / 128, DMODEL / 128), 256, 0, stream>>>(
      Yattn, Wot, bo, nullptr, nullptr, nullptr, out, nullptr, nullptr, DMODEL);
}